// Round 4
// baseline (320.151 us; speedup 1.0000x reference)
//
#include <hip/hip_runtime.h>
#include <cmath>

namespace {

constexpr int kB    = 8;
constexpr int kH    = 160;
constexpr int kW    = 160;
constexpr int kC    = 256;
constexpr int kWC   = kW * kC;
constexpr int kHWC  = kH * kW * kC;
constexpr int kN    = 1024;
constexpr int kCrop = 14;
constexpr int kPO   = 7;                     // pooled output is 7x7
constexpr int kOutPos = kN * kPO * kPO;      // 50176 pooled positions
constexpr int kBlocks = kOutPos / 4;         // 12544 (divisible by 8)

// One wave (64 lanes) per pooled output position; lane handles 4 channels
// (float4). 256-thread block = 4 waves = 4 pooled outputs.
//
// Occupancy-first design: all wave-uniform quantities (ROI scalars, corner
// row/col offsets, image base) are forced into SGPRs via readfirstlane, and
// only 8 float4 loads are live at a time (two groups of sy=0 / sy=1).
// Target <=64 VGPRs -> 8 waves/SIMD for latency hiding of the gather.
__global__ __launch_bounds__(256, 8) void roi_pool_kernel(
    const float* __restrict__ img,     // [B,H,W,C] NHWC
    const float* __restrict__ rois,    // [N,5]  (img_id, x0, y0, x1, y1)
    const float* __restrict__ iminfo,  // [N,2]  (H_img, W_img)
    float* __restrict__ out)           // [N,7,7,C]
{
    const int wave = threadIdx.x >> 6;
    const int lane = threadIdx.x & 63;

    // physical -> logical block remap (XCD-contiguous for per-ROI L2 reuse)
    const int xcd = blockIdx.x & 7;
    const int lb  = xcd * (kBlocks >> 3) + (blockIdx.x >> 3);

    const int p = lb * 4 + wave;               // pooled position (wave-uniform)
    const int n  = __builtin_amdgcn_readfirstlane(p / (kPO * kPO));
    const int r  = p - n * (kPO * kPO);
    const int ph = __builtin_amdgcn_readfirstlane(r / kPO);
    const int pw = __builtin_amdgcn_readfirstlane(r - ph * kPO);

    // Per-ROI scalars (wave-uniform)
    const float bidf = rois[n * 5 + 0];
    const float bx0  = rois[n * 5 + 1];
    const float by0  = rois[n * 5 + 2];
    const float bx1  = rois[n * 5 + 3];
    const float by1  = rois[n * 5 + 4];
    const float him  = iminfo[n * 2 + 0];
    const float wim  = iminfo[n * 2 + 1];
    const int b = __builtin_amdgcn_readfirstlane((int)bidf);

    const float y1 = by0 / him;
    const float x1 = bx0 / wim;
    const float y2 = by1 / him;
    const float x2 = bx1 / wim;

    const float ybase = y1 * (float)(kH - 1);
    const float xbase = x1 * (float)(kW - 1);
    const float ystep = ((y2 - y1) * (float)(kH - 1)) / (float)(kCrop - 1);
    const float xstep = ((x2 - x1) * (float)(kW - 1)) / (float)(kCrop - 1);

    float ylerp[2], xlerp[2];
    float vy[2], vx[2];
    int rowoff[4];   // element offsets of yl0,yh0,yl1,yh1 rows (SGPR)
    int coloff[4];   // element offsets of xl0,xh0,xl1,xh1 cols (SGPR)
#pragma unroll
    for (int s = 0; s < 2; ++s) {
        const float y = ybase + (float)(2 * ph + s) * ystep;
        vy[s] = ((y >= 0.0f) && (y <= (float)(kH - 1))) ? 1.0f : 0.0f;
        const float yf = floorf(y);
        ylerp[s] = y - yf;
        rowoff[2 * s + 0] = __builtin_amdgcn_readfirstlane(
            (int)fminf(fmaxf(yf, 0.0f), (float)(kH - 1)) * kWC);
        rowoff[2 * s + 1] = __builtin_amdgcn_readfirstlane(
            (int)fminf(fmaxf(yf + 1.0f, 0.0f), (float)(kH - 1)) * kWC);

        const float x = xbase + (float)(2 * pw + s) * xstep;
        vx[s] = ((x >= 0.0f) && (x <= (float)(kW - 1))) ? 1.0f : 0.0f;
        const float xf = floorf(x);
        xlerp[s] = x - xf;
        coloff[2 * s + 0] = __builtin_amdgcn_readfirstlane(
            (int)fminf(fmaxf(xf, 0.0f), (float)(kW - 1)) * kC);
        coloff[2 * s + 1] = __builtin_amdgcn_readfirstlane(
            (int)fminf(fmaxf(xf + 1.0f, 0.0f), (float)(kW - 1)) * kC);
    }

    const int c = lane * 4;                               // channel offset
    // image base: scalar part (b) in SGPR, lane part (c) the only VGPR offset
    const float* imgb = img + (size_t)(b * kHWC) + c;

    // acc starts at -INF: an all-valid window of negatives must yield the
    // negative max (invalid samples contribute literal 0 via the mask).
    float4 acc = make_float4(-INFINITY, -INFINITY, -INFINITY, -INFINITY);

#pragma unroll
    for (int sy = 0; sy < 2; ++sy) {
        const int r0 = rowoff[2 * sy + 0];
        const int r1 = rowoff[2 * sy + 1];
        // 8 loads of this sy-group issued back-to-back (saddr form: SGPR
        // base+row+col, VGPR offset = c)
        float4 d0, d1, d2, d3, d4, d5, d6, d7;
        d0 = *(const float4*)(imgb + r0 + coloff[0]);
        d1 = *(const float4*)(imgb + r0 + coloff[1]);
        d2 = *(const float4*)(imgb + r1 + coloff[0]);
        d3 = *(const float4*)(imgb + r1 + coloff[1]);
        d4 = *(const float4*)(imgb + r0 + coloff[2]);
        d5 = *(const float4*)(imgb + r0 + coloff[3]);
        d6 = *(const float4*)(imgb + r1 + coloff[2]);
        d7 = *(const float4*)(imgb + r1 + coloff[3]);

        const float yw = ylerp[sy];
#pragma unroll
        for (int sx = 0; sx < 2; ++sx) {
            const float4 tl = sx ? d4 : d0;
            const float4 tr = sx ? d5 : d1;
            const float4 bl = sx ? d6 : d2;
            const float4 br = sx ? d7 : d3;
            const float xw = xlerp[sx];
            const float m  = vy[sy] * vx[sx];   // 0 or 1
            const float t0 = tl.x + (tr.x - tl.x) * xw;
            const float t1 = tl.y + (tr.y - tl.y) * xw;
            const float t2 = tl.z + (tr.z - tl.z) * xw;
            const float t3 = tl.w + (tr.w - tl.w) * xw;
            const float b0 = bl.x + (br.x - bl.x) * xw;
            const float b1 = bl.y + (br.y - bl.y) * xw;
            const float b2 = bl.z + (br.z - bl.z) * xw;
            const float b3 = bl.w + (br.w - bl.w) * xw;
            acc.x = fmaxf(acc.x, (t0 + (b0 - t0) * yw) * m);
            acc.y = fmaxf(acc.y, (t1 + (b1 - t1) * yw) * m);
            acc.z = fmaxf(acc.z, (t2 + (b2 - t2) * yw) * m);
            acc.w = fmaxf(acc.w, (t3 + (b3 - t3) * yw) * m);
        }
    }

    // nontemporal: don't let the 51 MB output stream evict the gather
    // working set from L2
    float4* op = (float4*)(out + (size_t)p * kC + c);
    __builtin_nontemporal_store(acc.x, &op->x);
    __builtin_nontemporal_store(acc.y, &op->y);
    __builtin_nontemporal_store(acc.z, &op->z);
    __builtin_nontemporal_store(acc.w, &op->w);
}

} // namespace

extern "C" void kernel_launch(void* const* d_in, const int* in_sizes, int n_in,
                              void* d_out, int out_size, void* d_ws, size_t ws_size,
                              hipStream_t stream) {
    const float* img    = (const float*)d_in[0];   // (8,160,160,256) f32
    const float* rois   = (const float*)d_in[1];   // (1024,5) f32
    const float* iminfo = (const float*)d_in[2];   // (1024,2) f32
    float* out = (float*)d_out;                    // (1024,7,7,256) f32

    dim3 grid(kBlocks);   // 12544 blocks, 4 pooled outputs each
    dim3 block(256);
    roi_pool_kernel<<<grid, block, 0, stream>>>(img, rois, iminfo, out);
}